// Round 8
// baseline (1085.448 us; speedup 1.0000x reference)
//
#include <hip/hip_runtime.h>
#include <math.h>

// Problem constants
#define B_  2
#define N_  6
#define C_  64
#define FH_ 16
#define FW_ 44
#define D_  64
#define PIX (FH_*FW_)          // 704
#define BNI (B_*N_)            // 12
#define NPILLAR (BNI*PIX)      // 8448
#define NPOINT (NPILLAR*D_)    // 540672
#define BEVH 128
#define BEVW 128
#define BEVC (BEVH*BEVW)       // 16384
#define NCELL (B_*BEVC)        // 32768
#define PW 46                  // padded plane width
#define PP (18*PW)             // padded plane = 828 floats

#define NBLK 1024

typedef unsigned int u32;

__device__ __forceinline__ int rlane_i(int v, int l) {
    return __builtin_amdgcn_readlane(v, l);
}
__device__ __forceinline__ float rlane_f(float v, int l) {
    return __int_as_float(__builtin_amdgcn_readlane(__float_as_int(v), l));
}

__device__ __forceinline__ u32 aload(u32* p) {
    return __hip_atomic_load(p, __ATOMIC_ACQUIRE, __HIP_MEMORY_SCOPE_AGENT);
}
__device__ __forceinline__ void astore(u32* p, u32 v) {
    __hip_atomic_store(p, v, __ATOMIC_RELEASE, __HIP_MEMORY_SCOPE_AGENT);
}

// Software grid barrier: per-block arrival slots + block-0 scan + generation.
// Safe because __launch_bounds__(256,4) * grid 1024 == exact co-residency.
__device__ __forceinline__ void grid_sync(u32* arr, u32* gen, u32 g) {
    __syncthreads();
    if (threadIdx.x == 0) {
        __threadfence();                       // device-scope release
        astore(&arr[blockIdx.x], g);
    }
    if (blockIdx.x == 0) {
#pragma unroll
        for (int k = 0; k < 4; ++k) {
            u32 idx = (u32)threadIdx.x * 4u + (u32)k;
            while (aload(&arr[idx]) < g) __builtin_amdgcn_s_sleep(8);
        }
        __syncthreads();
        if (threadIdx.x == 0) {
            __threadfence();
            astore(gen, g);
        }
    } else {
        if (threadIdx.x == 0) {
            while (aload(gen) < g) __builtin_amdgcn_s_sleep(8);
        }
    }
    __syncthreads();
}

struct KArgs {
    const float *feat, *intr, *extr, *w1, *b1, *gma, *bta, *mu, *var, *w2, *b2;
    float* out;
    double* Mbuf;
    u32* barr;      // [NBLK]
    u32* gen;       // [1]
    u32* gcursor;   // [1]
    uint2* sorted;
    uint2* pc;
    float* x_t;
    float* hpAll;
    u32* counts;
    u32* offs;
    float* w2t;
};

// Phase-0 virtual blocks: [0,768) conv1 units, [768,900) transpose tiles,
// [900] M+w2t, [901,1029) counts-zero.
#define NV0 1029
#define NV1 2112                // depth: 4 pillars/unit
#define NV2 128                 // alloc: 256 cells/unit
#define NV3 4161                // zero(2048) + place(2112) + sentinel(1)
#define NV4 2112                // pool: 4 segments/unit

__global__ __launch_bounds__(256, 4) void k_mega(KArgs a) {
    const int tid  = threadIdx.x;
    const int lane = tid & 63;
    const int wv   = tid >> 6;
    u32 g = 0;

    __shared__ float smraw[4160];   // 16.6 KB: max(conv 2*828, tile 64*65)

    // ---------------- Phase 0: conv1 partials, x_t transpose, M, w2t, zeros
    {
        const int y0 = tid / FW_,        x0 = tid % FW_;
        const int y1 = (tid+256) / FW_,  x1 = (tid+256) % FW_;
        const int y2 = (tid+512) / FW_,  x2 = (tid+512) % FW_;
        const int rp0 = y0 * PW + x0, rp1 = y1 * PW + x1, rp2 = y2 * PW + x2;

        for (int vb = blockIdx.x; vb < NV0; vb += NBLK) {
            if (vb < 768) {
                const int bn = vb >> 6;
                const int ch = (vb >> 4) & 3;
                const int o0 = (vb & 15) * 4;
                const int c0 = ch * 16;
                float* lds = smraw;                   // [2][PP]
                for (int t = tid; t < 2 * PP; t += 256) lds[t] = 0.0f;
                __syncthreads();
                const float* fb = a.feat + ((size_t)bn * C_ + c0) * PIX;
                for (int t = tid; t < PIX; t += 256) {
                    const int yy = t / FW_, xx = t % FW_;
                    lds[(yy + 1) * PW + xx + 1] = fb[t];
                }
                __syncthreads();

                float a00=0,a01=0,a02=0,a03=0, a10=0,a11=0,a12=0,a13=0,
                      a20=0,a21=0,a22=0,a23=0;
                for (int i = 0; i < 16; ++i) {
                    float* cbuf = lds + (i & 1) * PP;
                    float* nbuf = lds + ((i & 1) ^ 1) * PP;
                    if (i < 15) {
                        const float* fp = fb + (i + 1) * PIX;
                        for (int t = tid; t < PIX; t += 256) {
                            const int yy = t / FW_, xx = t % FW_;
                            nbuf[(yy + 1) * PW + xx + 1] = fp[t];
                        }
                    }
                    const float* wr0 = a.w1 + ((size_t)(o0+0) * C_ + c0 + i) * 9;
                    const float* wr1 = a.w1 + ((size_t)(o0+1) * C_ + c0 + i) * 9;
                    const float* wr2 = a.w1 + ((size_t)(o0+2) * C_ + c0 + i) * 9;
                    const float* wr3 = a.w1 + ((size_t)(o0+3) * C_ + c0 + i) * 9;
#define CONV_SLOT(RP, A0, A1, A2, A3)                                          \
    {                                                                          \
        const float* bb = cbuf + (RP);                                         \
        const float n0=bb[0], n1=bb[1], n2=bb[2];                              \
        const float n3=bb[PW], n4=bb[PW+1], n5=bb[PW+2];                       \
        const float n6=bb[2*PW], n7=bb[2*PW+1], n8=bb[2*PW+2];                 \
        A0 += n0*wr0[0]+n1*wr0[1]+n2*wr0[2]+n3*wr0[3]+n4*wr0[4]                \
            + n5*wr0[5]+n6*wr0[6]+n7*wr0[7]+n8*wr0[8];                         \
        A1 += n0*wr1[0]+n1*wr1[1]+n2*wr1[2]+n3*wr1[3]+n4*wr1[4]                \
            + n5*wr1[5]+n6*wr1[6]+n7*wr1[7]+n8*wr1[8];                         \
        A2 += n0*wr2[0]+n1*wr2[1]+n2*wr2[2]+n3*wr2[3]+n4*wr2[4]                \
            + n5*wr2[5]+n6*wr2[6]+n7*wr2[7]+n8*wr2[8];                         \
        A3 += n0*wr3[0]+n1*wr3[1]+n2*wr3[2]+n3*wr3[3]+n4*wr3[4]                \
            + n5*wr3[5]+n6*wr3[6]+n7*wr3[7]+n8*wr3[8];                         \
    }
                    CONV_SLOT(rp0, a00, a01, a02, a03);
                    CONV_SLOT(rp1, a10, a11, a12, a13);
                    if (tid < PIX - 512) CONV_SLOT(rp2, a20, a21, a22, a23);
#undef CONV_SLOT
                    __syncthreads();
                }
                float* hp = a.hpAll + (size_t)ch * NPOINT + (size_t)bn * PIX * C_;
                *(float4*)&hp[(size_t)tid * C_ + o0]       = make_float4(a00,a01,a02,a03);
                *(float4*)&hp[(size_t)(tid+256) * C_ + o0] = make_float4(a10,a11,a12,a13);
                if (tid < PIX - 512)
                    *(float4*)&hp[(size_t)(tid+512) * C_ + o0] = make_float4(a20,a21,a22,a23);
            } else if (vb < 900) {
                const int u  = vb - 768;
                const int bn = u / 11;
                const int p0 = (u % 11) * 64;
                const int row4 = tid >> 6;
                float* tile = smraw;                  // [64][65]
#pragma unroll
                for (int k = 0; k < 16; ++k) {
                    const int c = k * 4 + row4;
                    tile[c * 65 + lane] = a.feat[((size_t)bn * C_ + c) * PIX + p0 + lane];
                }
                __syncthreads();
#pragma unroll
                for (int k = 0; k < 16; ++k) {
                    const int r = k * 4 + row4;
                    a.x_t[((size_t)bn * PIX + p0 + r) * C_ + lane] = tile[lane * 65 + r];
                }
            } else if (vb == 900) {
#pragma unroll
                for (int k = 0; k < 16; ++k) {
                    const int idx = k * 256 + tid;
                    const int d = idx >> 6, c = idx & 63;
                    a.w2t[c * D_ + d] = a.w2[idx];
                }
                if (tid < BNI) {
                    const float* K = &a.intr[tid * 9];
                    const double a00 = K[0], a01 = K[1], a02 = K[2];
                    const double a10 = K[3], a11 = K[4], a12 = K[5];
                    const double a20 = K[6], a21 = K[7], a22 = K[8];
                    const double det = a00 * (a11*a22 - a12*a21)
                                     - a01 * (a10*a22 - a12*a20)
                                     + a02 * (a10*a21 - a11*a20);
                    const double id = 1.0 / det;
                    double inv[9];
                    inv[0] = (a11*a22 - a12*a21) * id;
                    inv[1] = (a02*a21 - a01*a22) * id;
                    inv[2] = (a01*a12 - a02*a11) * id;
                    inv[3] = (a12*a20 - a10*a22) * id;
                    inv[4] = (a00*a22 - a02*a20) * id;
                    inv[5] = (a02*a10 - a00*a12) * id;
                    inv[6] = (a10*a21 - a11*a20) * id;
                    inv[7] = (a01*a20 - a00*a21) * id;
                    inv[8] = (a00*a11 - a01*a10) * id;
                    const float* E = &a.extr[tid * 16];
                    double* M = &a.Mbuf[tid * 9];
                    for (int r = 0; r < 3; ++r) {
                        const double r0 = E[r*4+0], r1 = E[r*4+1], r2 = E[r*4+2];
                        M[r*3+0] = r0*inv[0] + r1*inv[3] + r2*inv[6];
                        M[r*3+1] = r0*inv[1] + r1*inv[4] + r2*inv[7];
                        M[r*3+2] = r0*inv[2] + r1*inv[5] + r2*inv[8];
                    }
                }
            } else {
                const int u = vb - 901;
                a.counts[u * 256 + tid] = 0u;
                if (u == 0 && tid == 0) *a.gcursor = 0u;
            }
            __syncthreads();
        }
    }
    grid_sync(a.barr, a.gen, ++g);

    // ---------------- Phase 1: depth (BN+ReLU, 1x1 conv, softmax, geometry)
    for (int vb = blockIdx.x; vb < NV1; vb += NBLK) {
        const int pillar = vb * 4 + wv;
        const int bn = pillar / PIX;
        const int p  = pillar % PIX;
        const int yi = p / FW_;
        const int xi = p % FW_;
        const int d  = lane;

        float* hs = smraw;      // [4][64]
        {
            const size_t o = (size_t)pillar * C_ + d;
            float h = a.hpAll[o] + a.hpAll[NPOINT + o]
                    + a.hpAll[2 * (size_t)NPOINT + o]
                    + a.hpAll[3 * (size_t)NPOINT + o] + a.b1[d];
            const float sc = a.gma[d] / sqrtf(a.var[d] + 1e-5f);
            h = (h - a.mu[d]) * sc + a.bta[d];
            hs[wv * 64 + d] = h > 0.f ? h : 0.f;
        }
        __syncthreads();

        float logit = a.b2[d];
#pragma unroll
        for (int c = 0; c < C_; ++c) logit += hs[wv * 64 + c] * a.w2t[c * D_ + d];

        float m = logit;
#pragma unroll
        for (int off = 32; off; off >>= 1) m = fmaxf(m, __shfl_xor(m, off));
        float e = expf(logit - m);
        float s = e;
#pragma unroll
        for (int off = 32; off; off >>= 1) s += __shfl_xor(s, off);

        const double* M = &a.Mbuf[bn * 9];
        const double xn = (double)xi * (703.0 / 43.0);
        const double yn = (double)yi * 17.0;
        const double vx = M[0] * xn + M[1] * yn + M[2];
        const double vy = M[3] * xn + M[4] * yn + M[5];
        const double dd = 1.0 + (double)d * (59.0 / 63.0);
        const float* E = &a.extr[bn * 16];
        const double ex = dd * vx + (double)E[3];
        const double ey = dd * vy + (double)E[7];
        const int ix = (int)floor((ex + 51.2) * 1.25);
        const int iy = (int)floor((ey + 51.2) * 1.25);
        const bool valid = (ix >= 0) && (ix < BEVW) && (iy >= 0) && (iy < BEVH);

        const int i = pillar * D_ + d;
        uint2 rec;
        rec.x = __float_as_uint(e / s);
        if (valid) {
            const int cell = (bn / N_) * BEVC + iy * BEVW + ix;
            const u32 rank = atomicAdd(&a.counts[cell], 1u);
            rec.y = (rank << 15) | (u32)cell;
        } else {
            rec.y = 0xFFFFFFFFu;
        }
        a.pc[i] = rec;
        __syncthreads();
    }
    grid_sync(a.barr, a.gen, ++g);

    // ---------------- Phase 2: per-cell range allocation via wave cursor
    for (int vb = blockIdx.x; vb < NV2; vb += NBLK) {
        const int cell = vb * 256 + tid;
        const u32 len = a.counts[cell];
        u32 incl = len;
#pragma unroll
        for (int off = 1; off < 64; off <<= 1) {
            u32 t = __shfl_up(incl, off);
            if (lane >= off) incl += t;
        }
        u32 base = 0;
        if (lane == 63) base = atomicAdd(a.gcursor, incl);
        base = (u32)__shfl((int)base, 63);
        a.offs[cell] = base + incl - len;
    }
    grid_sync(a.barr, a.gen, ++g);

    // ---------------- Phase 3: selective zero, placement, sentinels
    for (int vb = blockIdx.x; vb < NV3; vb += NBLK) {
        if (vb < 2048) {
            const int gt = vb * 256 + tid;          // 2*64*4096 threads
            const int c4 = gt & 4095;
            const int bc = gt >> 12;                // b*64 + c
            const int b  = bc >> 6;
            const int cellbase = b * BEVC + (c4 << 2);
            const uint4 s4 = *(const uint4*)&a.offs[cellbase];
            const uint4 n4 = *(const uint4*)&a.counts[cellbase];
            float* dst = a.out + ((size_t)bc * BEVC) + (c4 << 2);
            if ((n4.x | n4.y | n4.z | n4.w) == 0u) {
                *(float4*)dst = make_float4(0.f, 0.f, 0.f, 0.f);
            } else {
                if (n4.x == 0u || (s4.x >> 6) != ((s4.x + n4.x - 1) >> 6)) dst[0] = 0.f;
                if (n4.y == 0u || (s4.y >> 6) != ((s4.y + n4.y - 1) >> 6)) dst[1] = 0.f;
                if (n4.z == 0u || (s4.z >> 6) != ((s4.z + n4.z - 1) >> 6)) dst[2] = 0.f;
                if (n4.w == 0u || (s4.w >> 6) != ((s4.w + n4.w - 1) >> 6)) dst[3] = 0.f;
            }
        } else if (vb < 4160) {
            const int i = (vb - 2048) * 256 + tid;  // < NPOINT exactly
            const uint2 rec = a.pc[i];
            if (rec.y != 0xFFFFFFFFu) {
                const u32 cell = rec.y & 0x7FFFu;
                const u32 rank = rec.y >> 15;
                const u32 pos  = a.offs[cell] + rank;
                uint2 o; o.x = rec.x; o.y = (cell << 14) | (u32)(i >> 6);
                a.sorted[pos] = o;
            }
        } else {
            const u32 total = *a.gcursor;
            if (tid < 128) {
                uint2 dummy; dummy.x = 0u; dummy.y = 0xFFFFFFFFu;
                a.sorted[total + tid] = dummy;
            }
            if (tid == 128) a.offs[NCELL] = total;
        }
    }
    grid_sync(a.barr, a.gen, ++g);

    // ---------------- Phase 4: balanced segment pool
    {
        const u32 P = a.offs[NCELL];
        const float* x_t = a.x_t;
        float* out = a.out;
        const uint2* sorted = a.sorted;
        for (int vb = blockIdx.x; vb < NV4; vb += NBLK) {
            const u32 j0 = ((u32)vb * 4u + (u32)wv) * 64u;
            if (j0 >= P) continue;

            const uint2 pr  = sorted[j0 + (u32)lane];
            const float myw = __uint_as_float(pr.x);
            const int mycell = (int)(pr.y >> 14);
            const int mypil  = (int)(pr.y & 0x3FFFu);

            const int prev_cell = (j0 > 0) ? (int)(sorted[j0 - 1].y >> 14) : -1;
            const int next_cell = (int)(sorted[j0 + 64].y >> 14);

            float acc = 0.f;
            int cur = rlane_i(mycell, 0);
            bool first = true;

            float xr0 = x_t[(size_t)rlane_i(mypil, 0) * C_ + lane];
            float xr1 = x_t[(size_t)rlane_i(mypil, 1) * C_ + lane];
            float xr2 = x_t[(size_t)rlane_i(mypil, 2) * C_ + lane];
            float xr3 = x_t[(size_t)rlane_i(mypil, 3) * C_ + lane];

#define DST(cc) (out + ((size_t)((cc) >> 14) * C_ + lane) * BEVC + ((cc) & (BEVC - 1)))
#define POOL_STEP(tt, xr)                                                     \
    {                                                                         \
        const float wb = rlane_f(myw, (tt));                                  \
        acc += wb * (xr);                                                     \
        const int nxt = ((tt) == 63) ? next_cell : rlane_i(mycell, (tt) + 1);\
        if ((tt) == 63 && nxt == cur) {                                       \
            if (cur < NCELL) atomicAdd(DST(cur), acc);                        \
        } else if (nxt != cur) {                                              \
            if (cur < NCELL) {                                                \
                if (first && cur == prev_cell) atomicAdd(DST(cur), acc);      \
                else *DST(cur) = acc;                                         \
            }                                                                 \
            acc = 0.f; first = false; cur = nxt;                              \
        }                                                                     \
    }
#pragma unroll
            for (int t4 = 0; t4 < 16; ++t4) {
                const int t = t4 * 4;
                float y0 = 0.f, y1 = 0.f, y2 = 0.f, y3 = 0.f;
                if (t4 < 15) {
                    y0 = x_t[(size_t)rlane_i(mypil, t + 4) * C_ + lane];
                    y1 = x_t[(size_t)rlane_i(mypil, t + 5) * C_ + lane];
                    y2 = x_t[(size_t)rlane_i(mypil, t + 6) * C_ + lane];
                    y3 = x_t[(size_t)rlane_i(mypil, t + 7) * C_ + lane];
                }
                POOL_STEP(t + 0, xr0);
                POOL_STEP(t + 1, xr1);
                POOL_STEP(t + 2, xr2);
                POOL_STEP(t + 3, xr3);
                xr0 = y0; xr1 = y1; xr2 = y2; xr3 = y3;
            }
#undef POOL_STEP
#undef DST
        }
    }
}

// ---------------------------------------------------------------------------
extern "C" void kernel_launch(void* const* d_in, const int* in_sizes, int n_in,
                              void* d_out, int out_size, void* d_ws, size_t ws_size,
                              hipStream_t stream) {
    KArgs ka;
    ka.feat = (const float*)d_in[0];
    ka.intr = (const float*)d_in[1];
    ka.extr = (const float*)d_in[2];
    ka.w1   = (const float*)d_in[3];
    ka.b1   = (const float*)d_in[4];
    ka.gma  = (const float*)d_in[5];
    ka.bta  = (const float*)d_in[6];
    ka.mu   = (const float*)d_in[7];
    ka.var  = (const float*)d_in[8];
    ka.w2   = (const float*)d_in[9];
    ka.b2   = (const float*)d_in[10];
    ka.out  = (float*)d_out;

    // workspace layout
    // [0, 864)        Mbuf (108 doubles)
    // [1024, 5120)    barrier arrival slots (1024 u32)
    // [5120, 5124)    gen
    // [5124, 5128)    gcursor
    // [8192, ...)     sorted, pc, x_t, hpAll, counts, offs, w2t
    ka.Mbuf    = (double*)d_ws;
    ka.barr    = (u32*)((char*)d_ws + 1024);
    ka.gen     = (u32*)((char*)d_ws + 5120);
    ka.gcursor = (u32*)((char*)d_ws + 5124);
    ka.sorted  = (uint2*)((char*)d_ws + 8192);                   // NPOINT+128
    ka.pc      = ka.sorted + NPOINT + 128;                       // NPOINT
    ka.x_t     = (float*)(ka.pc + NPOINT);                       // NPOINT
    ka.hpAll   = ka.x_t + NPOINT;                                // 4*NPOINT
    ka.counts  = (u32*)(ka.hpAll + 4 * (size_t)NPOINT);          // NCELL
    ka.offs    = ka.counts + NCELL;                              // NCELL+1
    ka.w2t     = (float*)(ka.offs + NCELL + 1);                  // 4096

    // zero barrier state (arr + gen + gcursor); d_ws is poisoned, not zeroed
    hipMemsetAsync((char*)d_ws + 1024, 0, 4104, stream);

    k_mega<<<NBLK, 256, 0, stream>>>(ka);

    (void)in_sizes; (void)n_in; (void)ws_size; (void)out_size;
}

// Round 9
// 120.615 us; speedup vs baseline: 8.9993x; 8.9993x over previous
//
#include <hip/hip_runtime.h>
#include <hip/hip_bf16.h>
#include <math.h>

// Problem constants
#define B_  2
#define N_  6
#define C_  64
#define FH_ 16
#define FW_ 44
#define D_  64
#define PIX (FH_*FW_)          // 704
#define BNI (B_*N_)            // 12
#define NPILLAR (BNI*PIX)      // 8448
#define NPOINT (NPILLAR*D_)    // 540672
#define BEVH 128
#define BEVW 128
#define BEVC (BEVH*BEVW)       // 16384
#define NCELL (B_*BEVC)        // 32768
#define PW 46                  // padded plane width
#define PP (18*PW)             // padded plane = 828 floats

typedef unsigned int u32;

__device__ __forceinline__ int rlane_i(int v, int l) {
    return __builtin_amdgcn_readlane(v, l);
}
__device__ __forceinline__ float rlane_f(float v, int l) {
    return __int_as_float(__builtin_amdgcn_readlane(__float_as_int(v), l));
}

// ---------------------------------------------------------------------------
// Kernel T: LDS-tiled transpose feat -> x_t, w2 transpose, zero counters,
// per-(b,n) fused M = R*inv(K) in double (block 132). Grid: 133 blocks.
// ---------------------------------------------------------------------------
__global__ __launch_bounds__(256) void k_transpose(const float* __restrict__ feat,
                                                   float* __restrict__ x_t,
                                                   const float* __restrict__ w2,
                                                   float* __restrict__ w2t,
                                                   u32* __restrict__ counts,
                                                   const float* __restrict__ intr,
                                                   const float* __restrict__ extr,
                                                   double* __restrict__ Mbuf) {
    const int tid = threadIdx.x;
    if (blockIdx.x < 132) {
        const int bn = blockIdx.x / 11;
        const int p0 = (blockIdx.x % 11) * 64;
        const int lane = tid & 63;
        const int row4 = tid >> 6;

        __shared__ float tile[64][65];
#pragma unroll
        for (int k = 0; k < 16; ++k) {
            const int c = k * 4 + row4;
            tile[c][lane] = feat[((size_t)bn * C_ + c) * PIX + p0 + lane];
        }
        __syncthreads();
#pragma unroll
        for (int k = 0; k < 16; ++k) {
            const int r = k * 4 + row4;
            x_t[((size_t)bn * PIX + p0 + r) * C_ + lane] = tile[lane][r];
        }
        if (blockIdx.x == 0) {
#pragma unroll
            for (int k = 0; k < 16; ++k) {
                const int idx = k * 256 + tid;
                const int d = idx >> 6, c = idx & 63;
                w2t[c * D_ + d] = w2[idx];
            }
        }
    } else if (tid < BNI) {
        const float* K = &intr[tid * 9];
        const double a00 = K[0], a01 = K[1], a02 = K[2];
        const double a10 = K[3], a11 = K[4], a12 = K[5];
        const double a20 = K[6], a21 = K[7], a22 = K[8];
        const double det = a00 * (a11 * a22 - a12 * a21)
                         - a01 * (a10 * a22 - a12 * a20)
                         + a02 * (a10 * a21 - a11 * a20);
        const double id = 1.0 / det;
        double inv[9];
        inv[0] = (a11 * a22 - a12 * a21) * id;
        inv[1] = (a02 * a21 - a01 * a22) * id;
        inv[2] = (a01 * a12 - a02 * a11) * id;
        inv[3] = (a12 * a20 - a10 * a22) * id;
        inv[4] = (a00 * a22 - a02 * a20) * id;
        inv[5] = (a02 * a10 - a00 * a12) * id;
        inv[6] = (a10 * a21 - a11 * a20) * id;
        inv[7] = (a01 * a20 - a00 * a21) * id;
        inv[8] = (a00 * a11 - a01 * a10) * id;
        const float* E = &extr[tid * 16];
        double* M = &Mbuf[tid * 9];
        for (int r = 0; r < 3; ++r) {
            const double r0 = E[r * 4 + 0], r1 = E[r * 4 + 1], r2 = E[r * 4 + 2];
            M[r * 3 + 0] = r0 * inv[0] + r1 * inv[3] + r2 * inv[6];
            M[r * 3 + 1] = r0 * inv[1] + r1 * inv[4] + r2 * inv[7];
            M[r * 3 + 2] = r0 * inv[2] + r1 * inv[5] + r2 * inv[8];
        }
    }
    const int gz = blockIdx.x * 256 + tid;
    if (gz < NCELL) counts[gz] = 0;
}

// ---------------------------------------------------------------------------
// Kernel A: conv1 (3x3 SAME), 4-way input-channel split, raw partial sums.
// Grid: 768 = bn(12) x og(16) x chunk(4). Block: 704 = 1 thread/pixel.
// ---------------------------------------------------------------------------
__global__ __launch_bounds__(704) void k_conv1(const float* __restrict__ feat,
                                               const float* __restrict__ w1,
                                               float* __restrict__ hpAll) {
    const int blk = blockIdx.x;
    const int bn  = blk >> 6;
    const int o0  = (blk & 15) * 4;
    const int ch  = (blk >> 4) & 3;
    const int c0  = ch * 16;
    const int tid = threadIdx.x;
    const int y   = tid / FW_;
    const int x   = tid % FW_;
    const int wpos = (y + 1) * PW + (x + 1);
    const int rpos = y * PW + x;

    __shared__ float xp[2][PP];
    for (int t = tid; t < 2 * PP; t += 704) ((float*)xp)[t] = 0.0f;

    const float* fbase = feat + ((size_t)bn * C_ + c0) * PIX + tid;
    float vload = fbase[0];
    __syncthreads();
    xp[0][wpos] = vload;
    vload = fbase[PIX];
    __syncthreads();

    float acc0 = 0.f, acc1 = 0.f, acc2 = 0.f, acc3 = 0.f;

#pragma unroll 2
    for (int i = 0; i < 16; ++i) {
        const int cb = i & 1;
        if (i < 15) xp[cb ^ 1][wpos] = vload;
        if (i < 14) vload = fbase[(i + 2) * PIX];

        const float* bb = &xp[cb][rpos];
        const float n0 = bb[0],      n1 = bb[1],      n2 = bb[2];
        const float n3 = bb[PW],     n4 = bb[PW+1],   n5 = bb[PW+2];
        const float n6 = bb[2*PW],   n7 = bb[2*PW+1], n8 = bb[2*PW+2];

        const float* wr0 = w1 + ((size_t)(o0 + 0) * C_ + c0 + i) * 9;
        const float* wr1 = w1 + ((size_t)(o0 + 1) * C_ + c0 + i) * 9;
        const float* wr2 = w1 + ((size_t)(o0 + 2) * C_ + c0 + i) * 9;
        const float* wr3 = w1 + ((size_t)(o0 + 3) * C_ + c0 + i) * 9;
        acc0 += n0*wr0[0] + n1*wr0[1] + n2*wr0[2] + n3*wr0[3] + n4*wr0[4]
              + n5*wr0[5] + n6*wr0[6] + n7*wr0[7] + n8*wr0[8];
        acc1 += n0*wr1[0] + n1*wr1[1] + n2*wr1[2] + n3*wr1[3] + n4*wr1[4]
              + n5*wr1[5] + n6*wr1[6] + n7*wr1[7] + n8*wr1[8];
        acc2 += n0*wr2[0] + n1*wr2[1] + n2*wr2[2] + n3*wr2[3] + n4*wr2[4]
              + n5*wr2[5] + n6*wr2[6] + n7*wr2[7] + n8*wr2[8];
        acc3 += n0*wr3[0] + n1*wr3[1] + n2*wr3[2] + n3*wr3[3] + n4*wr3[4]
              + n5*wr3[5] + n6*wr3[6] + n7*wr3[7] + n8*wr3[8];
        __syncthreads();
    }

    float4 r; r.x = acc0; r.y = acc1; r.z = acc2; r.w = acc3;
    *(float4*)&hpAll[(size_t)ch * NPOINT + ((size_t)(bn * PIX + tid)) * C_ + o0] = r;
}

// ---------------------------------------------------------------------------
// Kernel D: sum 4 partials + bias + BN + ReLU -> 1x1 conv -> softmax ->
// geometry (ego = d*v + t) -> packed point record {w, rank<<15|cell}.
// ---------------------------------------------------------------------------
__global__ __launch_bounds__(256) void k_depth(const float* __restrict__ hpAll,
                                               const float* __restrict__ b1,
                                               const float* __restrict__ gma,
                                               const float* __restrict__ bta,
                                               const float* __restrict__ mu,
                                               const float* __restrict__ var,
                                               const float* __restrict__ w2t,
                                               const float* __restrict__ b2,
                                               const double* __restrict__ Mbuf,
                                               const float* __restrict__ extr,
                                               uint2* __restrict__ pc,
                                               u32* __restrict__ counts) {
    const int wv = threadIdx.x >> 6;
    const int d  = threadIdx.x & 63;
    const int pillar = blockIdx.x * 4 + wv;
    const int bn = pillar / PIX;
    const int p  = pillar % PIX;
    const int yi = p / FW_;
    const int xi = p % FW_;

    __shared__ float hs[4][C_];
    {
        const size_t o = (size_t)pillar * C_ + d;
        float h = hpAll[o] + hpAll[NPOINT + o] + hpAll[2 * (size_t)NPOINT + o]
                + hpAll[3 * (size_t)NPOINT + o] + b1[d];
        const float sc = gma[d] / sqrtf(var[d] + 1e-5f);
        h = (h - mu[d]) * sc + bta[d];
        hs[wv][d] = h > 0.f ? h : 0.f;
    }
    __syncthreads();

    float logit = b2[d];
#pragma unroll
    for (int c = 0; c < C_; ++c) logit += hs[wv][c] * w2t[c * D_ + d];

    float m = logit;
#pragma unroll
    for (int off = 32; off; off >>= 1) m = fmaxf(m, __shfl_xor(m, off));
    float e = expf(logit - m);
    float s = e;
#pragma unroll
    for (int off = 32; off; off >>= 1) s += __shfl_xor(s, off);

    // geometry: ego = d * (M*(x,y,1)) + t
    const double* M = &Mbuf[bn * 9];
    const double xn = (double)xi * (703.0 / 43.0);
    const double yn = (double)yi * 17.0;
    const double vx = M[0] * xn + M[1] * yn + M[2];
    const double vy = M[3] * xn + M[4] * yn + M[5];
    const double dd = 1.0 + (double)d * (59.0 / 63.0);
    const float* E = &extr[bn * 16];
    const double ex = dd * vx + (double)E[3];
    const double ey = dd * vy + (double)E[7];
    const int ix = (int)floor((ex + 51.2) * 1.25);
    const int iy = (int)floor((ey + 51.2) * 1.25);
    const bool valid = (ix >= 0) && (ix < BEVW) && (iy >= 0) && (iy < BEVH);

    const int i = pillar * D_ + d;
    uint2 rec;
    rec.x = __float_as_uint(e / s);
    if (valid) {
        const int cell = (bn / N_) * BEVC + iy * BEVW + ix;
        const u32 rank = atomicAdd(&counts[cell], 1u);
        rec.y = (rank << 15) | (u32)cell;
    } else {
        rec.y = 0xFFFFFFFFu;
    }
    pc[i] = rec;
}

// ---------------------------------------------------------------------------
// Kernel S: single-block scan (32 cells/thread); writes dummy sentinels.
// ---------------------------------------------------------------------------
__global__ __launch_bounds__(1024) void k_scan(const u32* __restrict__ counts,
                                               u32* __restrict__ offsets,
                                               uint2* __restrict__ sorted) {
    const int tid  = threadIdx.x;
    const int lane = tid & 63;
    const int wid  = tid >> 6;
    const int base = tid * 32;

    u32 v[32];
    u32 run = 0;
#pragma unroll
    for (int k = 0; k < 32; ++k) {
        u32 t = counts[base + k];
        v[k] = run;
        run += t;
    }

    u32 incl = run;
#pragma unroll
    for (int off = 1; off < 64; off <<= 1) {
        u32 t = __shfl_up(incl, off);
        if (lane >= off) incl += t;
    }
    const u32 wexcl = incl - run;

    __shared__ u32 wtot[16], web[16];
    if (lane == 63) wtot[wid] = incl;
    __syncthreads();
    if (tid == 0) {
        u32 s = 0;
        for (int j = 0; j < 16; ++j) { u32 t = wtot[j]; web[j] = s; s += t; }
    }
    __syncthreads();
    const u32 tbase = web[wid] + wexcl;

#pragma unroll
    for (int k = 0; k < 32; ++k) offsets[base + k] = tbase + v[k];

    const u32 total = web[15] + wtot[15];
    if (tid == 1023) offsets[NCELL] = total;
    if (tid < 128) {
        uint2 dummy; dummy.x = 0u; dummy.y = 0xFFFFFFFFu;  // cell 0x3FFFF >= NCELL
        sorted[total + tid] = dummy;
    }
}

// ---------------------------------------------------------------------------
// Kernel Z: zero only the output cells k_pool won't plain-store:
// empty cells and segment-boundary-spanning cells.
// ---------------------------------------------------------------------------
__global__ __launch_bounds__(256) void k_zero(const u32* __restrict__ offsets,
                                              const u32* __restrict__ counts,
                                              float* __restrict__ out) {
    const int t  = blockIdx.x * 256 + threadIdx.x;   // < 2*64*4096
    const int c4 = t & 4095;
    const int bc = t >> 12;                          // b*64 + c
    const int b  = bc >> 6;
    const int cellbase = b * BEVC + (c4 << 2);

    const uint4 s4 = *(const uint4*)&offsets[cellbase];
    const uint4 n4 = *(const uint4*)&counts[cellbase];
    float* dst = out + ((size_t)bc * BEVC) + (c4 << 2);

    if ((n4.x | n4.y | n4.z | n4.w) == 0u) {
        *(float4*)dst = make_float4(0.f, 0.f, 0.f, 0.f);
        return;
    }
    if (n4.x == 0u || (s4.x >> 6) != ((s4.x + n4.x - 1) >> 6)) dst[0] = 0.f;
    if (n4.y == 0u || (s4.y >> 6) != ((s4.y + n4.y - 1) >> 6)) dst[1] = 0.f;
    if (n4.z == 0u || (s4.z >> 6) != ((s4.z + n4.z - 1) >> 6)) dst[2] = 0.f;
    if (n4.w == 0u || (s4.w >> 6) != ((s4.w + n4.w - 1) >> 6)) dst[3] = 0.f;
}

// ---------------------------------------------------------------------------
// Kernel P: atomic-free placement using ranks; writes packed uint2.
// ---------------------------------------------------------------------------
__global__ void k_place(const uint2* __restrict__ pc,
                        const u32* __restrict__ offsets,
                        uint2* __restrict__ sorted) {
    const int i = blockIdx.x * 256 + threadIdx.x;
    if (i >= NPOINT) return;
    const uint2 rec = pc[i];
    if (rec.y != 0xFFFFFFFFu) {
        const u32 cell = rec.y & 0x7FFFu;
        const u32 rank = rec.y >> 15;
        const u32 pos  = offsets[cell] + rank;
        uint2 o; o.x = rec.x; o.y = (cell << 14) | (u32)(i >> 6);
        sorted[pos] = o;
    }
}

// ---------------------------------------------------------------------------
// Kernel G: balanced segment pool, boundary-ballot edition.
// One wave per 64-point segment; lane = channel. Run boundaries precomputed
// as a 64-bit ballot (scalar flush test, SALU); 8-deep register pipeline on
// the x_t row gather; flush logic only executes at run ends.
// ---------------------------------------------------------------------------
__global__ __launch_bounds__(256) void k_pool(const uint2* __restrict__ sorted,
                                              const u32* __restrict__ offsets,
                                              const float* __restrict__ x_t,
                                              float* __restrict__ out) {
    const u32 P = offsets[NCELL];
    const int wv   = threadIdx.x >> 6;
    const int lane = threadIdx.x & 63;
    const u32 j0   = ((u32)blockIdx.x * 4u + (u32)wv) * 64u;
    if (j0 >= P) return;

    const uint2 pr  = sorted[j0 + (u32)lane];
    const float myw = __uint_as_float(pr.x);
    const int mycell = (int)(pr.y >> 14);
    int mypil = (int)(pr.y & 0x3FFFu);
    if (mypil >= NPILLAR) mypil = 0;          // dummy sentinel rows (w = 0)

    const int prev_cell = (j0 > 0) ? (int)(sorted[j0 - 1].y >> 14) : -1;
    const int next_cell = (int)(sorted[j0 + 64].y >> 14);

    // run-start ballot: bit t == 1 iff a new run starts at t
    const int upc = __shfl_up(mycell, 1);
    const unsigned long long bm = __ballot(lane == 0 || mycell != upc);

    float xr[8];
#pragma unroll
    for (int t = 0; t < 8; ++t)
        xr[t] = x_t[(size_t)rlane_i(mypil, t) * C_ + lane];

    float acc = 0.f;
    bool first = true;

#pragma unroll
    for (int t = 0; t < 64; ++t) {
        acc += rlane_f(myw, t) * xr[t & 7];
        if (t + 8 < 64)
            xr[t & 7] = x_t[(size_t)rlane_i(mypil, t + 8) * C_ + lane];
        const bool flush = (t == 63) || ((bm >> (t + 1)) & 1ull);
        if (flush) {
            const int cc = rlane_i(mycell, t);
            if (cc < NCELL) {
                float* dst = out + ((size_t)(cc >> 14) * C_ + lane) * BEVC
                           + (cc & (BEVC - 1));
                const bool spans = (first && cc == prev_cell)
                                || (t == 63 && next_cell == cc);
                if (spans) atomicAdd(dst, acc);
                else *dst = acc;
            }
            acc = 0.f;
            first = false;
        }
    }
}

// ---------------------------------------------------------------------------
extern "C" void kernel_launch(void* const* d_in, const int* in_sizes, int n_in,
                              void* d_out, int out_size, void* d_ws, size_t ws_size,
                              hipStream_t stream) {
    const float* feat  = (const float*)d_in[0];
    const float* intr  = (const float*)d_in[1];
    const float* extr  = (const float*)d_in[2];
    const float* w1    = (const float*)d_in[3];
    const float* b1    = (const float*)d_in[4];
    const float* gma   = (const float*)d_in[5];
    const float* bta   = (const float*)d_in[6];
    const float* mu    = (const float*)d_in[7];
    const float* var   = (const float*)d_in[8];
    const float* w2    = (const float*)d_in[9];
    const float* b2    = (const float*)d_in[10];
    float* out = (float*)d_out;

    // workspace layout (8B-aligned first)
    double* Mbuf   = (double*)d_ws;                                  // 1 KiB
    uint2*  sorted = (uint2*)((char*)d_ws + 1024);                   // NPOINT+128
    uint2*  pc     = sorted + NPOINT + 128;                          // NPOINT
    float*  x_t    = (float*)(pc + NPOINT);                          // NPOINT
    float*  hpAll  = x_t + NPOINT;                                   // 4*NPOINT
    u32*    counts = (u32*)(hpAll + 4 * (size_t)NPOINT);             // NCELL
    u32*    offs   = counts + NCELL;                                 // NCELL+1
    float*  w2t    = (float*)(offs + NCELL + 1);                     // 4096

    k_transpose<<<133, 256, 0, stream>>>(feat, x_t, w2, w2t, counts, intr, extr, Mbuf);
    k_conv1<<<BNI * 64, 704, 0, stream>>>(feat, w1, hpAll);
    k_depth<<<NPILLAR / 4, 256, 0, stream>>>(hpAll, b1, gma, bta, mu, var,
                                             w2t, b2, Mbuf, extr, pc, counts);
    k_scan<<<1, 1024, 0, stream>>>(counts, offs, sorted);
    k_zero<<<2048, 256, 0, stream>>>(offs, counts, out);
    k_place<<<(NPOINT + 255) / 256, 256, 0, stream>>>(pc, offs, sorted);
    k_pool<<<NPOINT / 64 / 4, 256, 0, stream>>>(sorted, offs, x_t, out);

    (void)in_sizes; (void)n_in; (void)ws_size; (void)out_size;
}

// Round 10
// 111.889 us; speedup vs baseline: 9.7011x; 1.0780x over previous
//
#include <hip/hip_runtime.h>
#include <hip/hip_bf16.h>
#include <math.h>

// Problem constants
#define B_  2
#define N_  6
#define C_  64
#define FH_ 16
#define FW_ 44
#define D_  64
#define PIX (FH_*FW_)          // 704
#define BNI (B_*N_)            // 12
#define NPILLAR (BNI*PIX)      // 8448
#define NPOINT (NPILLAR*D_)    // 540672
#define BEVH 128
#define BEVW 128
#define BEVC (BEVH*BEVW)       // 16384
#define NCELL (B_*BEVC)        // 32768
#define PW 46                  // padded plane width
#define PP (18*PW)             // padded plane = 828 floats

typedef unsigned int u32;

__device__ __forceinline__ int rlane_i(int v, int l) {
    return __builtin_amdgcn_readlane(v, l);
}
__device__ __forceinline__ float rlane_f(float v, int l) {
    return __int_as_float(__builtin_amdgcn_readlane(__float_as_int(v), l));
}

// ---------------------------------------------------------------------------
// K1: fused init + conv1.
// blocks [0,768): conv1, 16-cin chunk, ALL planes staged once, 1 barrier.
//   (blocks 0..127 also zero the cell counters first - independent work)
// blocks [768,900): LDS-tiled transpose feat -> x_t
// block 900: w2 transpose + fused M = R*inv(K) + gcursor reset
// ---------------------------------------------------------------------------
__global__ __launch_bounds__(256) void k_init_conv(const float* __restrict__ feat,
                                                   const float* __restrict__ w1,
                                                   float* __restrict__ hpAll,
                                                   float* __restrict__ x_t,
                                                   const float* __restrict__ w2,
                                                   float* __restrict__ w2t,
                                                   u32* __restrict__ counts,
                                                   u32* __restrict__ gcursor,
                                                   const float* __restrict__ intr,
                                                   const float* __restrict__ extr,
                                                   double* __restrict__ Mbuf) {
    const int blk = blockIdx.x;
    const int tid = threadIdx.x;

    __shared__ float smem[16 * PP];          // 52,992 B (3 blocks/CU)

    if (blk < 768) {
        if (blk < 128) counts[blk * 256 + tid] = 0u;   // independent init

        const int bn = blk >> 6;
        const int ch = (blk >> 4) & 3;
        const int o0 = (blk & 15) * 4;
        const int c0 = ch * 16;

        // zero whole LDS (halo), then stage 16 planes' interiors
        for (int t = tid; t < 16 * PP; t += 256) smem[t] = 0.0f;
        __syncthreads();

        const int y0 = tid / FW_,          x0 = tid % FW_;
        const int y1 = (tid + 256) / FW_,  x1 = (tid + 256) % FW_;
        const int y2 = (tid + 512) / FW_,  x2 = (tid + 512) % FW_;
        const int wp0 = (y0 + 1) * PW + x0 + 1;
        const int wp1 = (y1 + 1) * PW + x1 + 1;
        const int wp2 = (y2 + 1) * PW + x2 + 1;
        const int rp0 = y0 * PW + x0;
        const int rp1 = y1 * PW + x1;
        const int rp2 = y2 * PW + x2;

        const float* fb = feat + ((size_t)bn * C_ + c0) * PIX;
#pragma unroll
        for (int pl = 0; pl < 16; ++pl) {
            smem[pl * PP + wp0] = fb[pl * PIX + tid];
            smem[pl * PP + wp1] = fb[pl * PIX + tid + 256];
            if (tid < PIX - 512) smem[pl * PP + wp2] = fb[pl * PIX + tid + 512];
        }
        __syncthreads();                      // the ONLY compute barrier

        float a00=0,a01=0,a02=0,a03=0, a10=0,a11=0,a12=0,a13=0,
              a20=0,a21=0,a22=0,a23=0;
#pragma unroll 4
        for (int i = 0; i < 16; ++i) {
            const float* wr0 = w1 + ((size_t)(o0 + 0) * C_ + c0 + i) * 9;
            const float* wr1 = w1 + ((size_t)(o0 + 1) * C_ + c0 + i) * 9;
            const float* wr2 = w1 + ((size_t)(o0 + 2) * C_ + c0 + i) * 9;
            const float* wr3 = w1 + ((size_t)(o0 + 3) * C_ + c0 + i) * 9;
            const float* pb = &smem[i * PP];
#define CONV_SLOT(RP, A0, A1, A2, A3)                                          \
    {                                                                          \
        const float* bb = pb + (RP);                                           \
        const float n0=bb[0], n1=bb[1], n2=bb[2];                              \
        const float n3=bb[PW], n4=bb[PW+1], n5=bb[PW+2];                       \
        const float n6=bb[2*PW], n7=bb[2*PW+1], n8=bb[2*PW+2];                 \
        A0 += n0*wr0[0]+n1*wr0[1]+n2*wr0[2]+n3*wr0[3]+n4*wr0[4]                \
            + n5*wr0[5]+n6*wr0[6]+n7*wr0[7]+n8*wr0[8];                         \
        A1 += n0*wr1[0]+n1*wr1[1]+n2*wr1[2]+n3*wr1[3]+n4*wr1[4]                \
            + n5*wr1[5]+n6*wr1[6]+n7*wr1[7]+n8*wr1[8];                         \
        A2 += n0*wr2[0]+n1*wr2[1]+n2*wr2[2]+n3*wr2[3]+n4*wr2[4]                \
            + n5*wr2[5]+n6*wr2[6]+n7*wr2[7]+n8*wr2[8];                         \
        A3 += n0*wr3[0]+n1*wr3[1]+n2*wr3[2]+n3*wr3[3]+n4*wr3[4]                \
            + n5*wr3[5]+n6*wr3[6]+n7*wr3[7]+n8*wr3[8];                         \
    }
            CONV_SLOT(rp0, a00, a01, a02, a03);
            CONV_SLOT(rp1, a10, a11, a12, a13);
            if (tid < PIX - 512) CONV_SLOT(rp2, a20, a21, a22, a23);
#undef CONV_SLOT
        }
        float* hp = hpAll + (size_t)ch * NPOINT + (size_t)bn * PIX * C_;
        *(float4*)&hp[(size_t)tid * C_ + o0]         = make_float4(a00,a01,a02,a03);
        *(float4*)&hp[(size_t)(tid + 256) * C_ + o0] = make_float4(a10,a11,a12,a13);
        if (tid < PIX - 512)
            *(float4*)&hp[(size_t)(tid + 512) * C_ + o0] = make_float4(a20,a21,a22,a23);
    } else if (blk < 900) {
        const int u  = blk - 768;
        const int bn = u / 11;
        const int p0 = (u % 11) * 64;
        const int lane = tid & 63;
        const int row4 = tid >> 6;
        float* tile = smem;                   // [64][65]
#pragma unroll
        for (int k = 0; k < 16; ++k) {
            const int c = k * 4 + row4;
            tile[c * 65 + lane] = feat[((size_t)bn * C_ + c) * PIX + p0 + lane];
        }
        __syncthreads();
#pragma unroll
        for (int k = 0; k < 16; ++k) {
            const int r = k * 4 + row4;
            x_t[((size_t)bn * PIX + p0 + r) * C_ + lane] = tile[lane * 65 + r];
        }
    } else {
#pragma unroll
        for (int k = 0; k < 16; ++k) {
            const int idx = k * 256 + tid;
            const int d = idx >> 6, c = idx & 63;
            w2t[c * D_ + d] = w2[idx];
        }
        if (tid == 0) *gcursor = 0u;
        if (tid < BNI) {
            const float* K = &intr[tid * 9];
            const double a00 = K[0], a01 = K[1], a02 = K[2];
            const double a10 = K[3], a11 = K[4], a12 = K[5];
            const double a20 = K[6], a21 = K[7], a22 = K[8];
            const double det = a00 * (a11 * a22 - a12 * a21)
                             - a01 * (a10 * a22 - a12 * a20)
                             + a02 * (a10 * a21 - a11 * a20);
            const double id = 1.0 / det;
            double inv[9];
            inv[0] = (a11 * a22 - a12 * a21) * id;
            inv[1] = (a02 * a21 - a01 * a22) * id;
            inv[2] = (a01 * a12 - a02 * a11) * id;
            inv[3] = (a12 * a20 - a10 * a22) * id;
            inv[4] = (a00 * a22 - a02 * a20) * id;
            inv[5] = (a02 * a10 - a00 * a12) * id;
            inv[6] = (a10 * a21 - a11 * a20) * id;
            inv[7] = (a01 * a20 - a00 * a21) * id;
            inv[8] = (a00 * a11 - a01 * a10) * id;
            const float* E = &extr[tid * 16];
            double* M = &Mbuf[tid * 9];
            for (int r = 0; r < 3; ++r) {
                const double r0 = E[r*4+0], r1 = E[r*4+1], r2 = E[r*4+2];
                M[r*3+0] = r0*inv[0] + r1*inv[3] + r2*inv[6];
                M[r*3+1] = r0*inv[1] + r1*inv[4] + r2*inv[7];
                M[r*3+2] = r0*inv[2] + r1*inv[5] + r2*inv[8];
            }
        }
    }
}

// ---------------------------------------------------------------------------
// K2: depth — sum 4 partials + bias + BN + ReLU -> 1x1 conv -> softmax ->
// geometry (ego = d*v + t) -> packed point record {w, rank<<15|cell}.
// ---------------------------------------------------------------------------
__global__ __launch_bounds__(256) void k_depth(const float* __restrict__ hpAll,
                                               const float* __restrict__ b1,
                                               const float* __restrict__ gma,
                                               const float* __restrict__ bta,
                                               const float* __restrict__ mu,
                                               const float* __restrict__ var,
                                               const float* __restrict__ w2t,
                                               const float* __restrict__ b2,
                                               const double* __restrict__ Mbuf,
                                               const float* __restrict__ extr,
                                               uint2* __restrict__ pc,
                                               u32* __restrict__ counts) {
    const int wv = threadIdx.x >> 6;
    const int d  = threadIdx.x & 63;
    const int pillar = blockIdx.x * 4 + wv;
    const int bn = pillar / PIX;
    const int p  = pillar % PIX;
    const int yi = p / FW_;
    const int xi = p % FW_;

    __shared__ float hs[4][C_];
    {
        const size_t o = (size_t)pillar * C_ + d;
        float h = hpAll[o] + hpAll[NPOINT + o] + hpAll[2 * (size_t)NPOINT + o]
                + hpAll[3 * (size_t)NPOINT + o] + b1[d];
        const float sc = gma[d] / sqrtf(var[d] + 1e-5f);
        h = (h - mu[d]) * sc + bta[d];
        hs[wv][d] = h > 0.f ? h : 0.f;
    }
    __syncthreads();

    float logit = b2[d];
#pragma unroll
    for (int c = 0; c < C_; ++c) logit += hs[wv][c] * w2t[c * D_ + d];

    float m = logit;
#pragma unroll
    for (int off = 32; off; off >>= 1) m = fmaxf(m, __shfl_xor(m, off));
    float e = expf(logit - m);
    float s = e;
#pragma unroll
    for (int off = 32; off; off >>= 1) s += __shfl_xor(s, off);

    const double* M = &Mbuf[bn * 9];
    const double xn = (double)xi * (703.0 / 43.0);
    const double yn = (double)yi * 17.0;
    const double vx = M[0] * xn + M[1] * yn + M[2];
    const double vy = M[3] * xn + M[4] * yn + M[5];
    const double dd = 1.0 + (double)d * (59.0 / 63.0);
    const float* E = &extr[bn * 16];
    const double ex = dd * vx + (double)E[3];
    const double ey = dd * vy + (double)E[7];
    const int ix = (int)floor((ex + 51.2) * 1.25);
    const int iy = (int)floor((ey + 51.2) * 1.25);
    const bool valid = (ix >= 0) && (ix < BEVW) && (iy >= 0) && (iy < BEVH);

    const int i = pillar * D_ + d;
    uint2 rec;
    rec.x = __float_as_uint(e / s);
    if (valid) {
        const int cell = (bn / N_) * BEVC + iy * BEVW + ix;
        const u32 rank = atomicAdd(&counts[cell], 1u);
        rec.y = (rank << 15) | (u32)cell;
    } else {
        rec.y = 0xFFFFFFFFu;
    }
    pc[i] = rec;
}

// ---------------------------------------------------------------------------
// K3: per-cell range allocation via wave-scan + global cursor (order-free;
// pool only needs per-cell contiguity). 128 blocks x 256.
// ---------------------------------------------------------------------------
__global__ __launch_bounds__(256) void k_alloc(const u32* __restrict__ counts,
                                               u32* __restrict__ offs,
                                               u32* __restrict__ gcursor) {
    const int cell = blockIdx.x * 256 + threadIdx.x;
    const int lane = threadIdx.x & 63;
    const u32 len = counts[cell];
    u32 incl = len;
#pragma unroll
    for (int off = 1; off < 64; off <<= 1) {
        u32 t = __shfl_up(incl, off);
        if (lane >= off) incl += t;
    }
    u32 base = 0;
    if (lane == 63) base = atomicAdd(gcursor, incl);
    base = (u32)__shfl((int)base, 63);
    offs[cell] = base + incl - len;
}

// ---------------------------------------------------------------------------
// K4: fused selective-zero + placement + sentinels. 4161 blocks.
// ---------------------------------------------------------------------------
__global__ __launch_bounds__(256) void k_zero_place(const uint2* __restrict__ pc,
                                                    const u32* __restrict__ offs,
                                                    const u32* __restrict__ counts,
                                                    const u32* __restrict__ gcursor,
                                                    uint2* __restrict__ sorted,
                                                    u32* __restrict__ offs_end,
                                                    float* __restrict__ out) {
    const int blk = blockIdx.x;
    const int tid = threadIdx.x;
    if (blk < 2048) {
        const int gt = blk * 256 + tid;
        const int c4 = gt & 4095;
        const int bc = gt >> 12;
        const int b  = bc >> 6;
        const int cellbase = b * BEVC + (c4 << 2);
        const uint4 s4 = *(const uint4*)&offs[cellbase];
        const uint4 n4 = *(const uint4*)&counts[cellbase];
        float* dst = out + ((size_t)bc * BEVC) + (c4 << 2);
        if ((n4.x | n4.y | n4.z | n4.w) == 0u) {
            *(float4*)dst = make_float4(0.f, 0.f, 0.f, 0.f);
        } else {
            if (n4.x == 0u || (s4.x >> 6) != ((s4.x + n4.x - 1) >> 6)) dst[0] = 0.f;
            if (n4.y == 0u || (s4.y >> 6) != ((s4.y + n4.y - 1) >> 6)) dst[1] = 0.f;
            if (n4.z == 0u || (s4.z >> 6) != ((s4.z + n4.z - 1) >> 6)) dst[2] = 0.f;
            if (n4.w == 0u || (s4.w >> 6) != ((s4.w + n4.w - 1) >> 6)) dst[3] = 0.f;
        }
    } else if (blk < 4160) {
        const int i = (blk - 2048) * 256 + tid;     // < NPOINT exactly
        const uint2 rec = pc[i];
        if (rec.y != 0xFFFFFFFFu) {
            const u32 cell = rec.y & 0x7FFFu;
            const u32 rank = rec.y >> 15;
            const u32 pos  = offs[cell] + rank;
            uint2 o; o.x = rec.x; o.y = (cell << 14) | (u32)(i >> 6);
            sorted[pos] = o;
        }
    } else {
        const u32 total = *gcursor;
        if (tid < 128) {
            uint2 dummy; dummy.x = 0u; dummy.y = 0xFFFFFFFFu;
            sorted[total + tid] = dummy;
        }
        if (tid == 128) *offs_end = total;
    }
}

// ---------------------------------------------------------------------------
// K5: balanced segment pool (boundary ballot + 8-deep pipeline).
// ---------------------------------------------------------------------------
__global__ __launch_bounds__(256) void k_pool(const uint2* __restrict__ sorted,
                                              const u32* __restrict__ offsets,
                                              const float* __restrict__ x_t,
                                              float* __restrict__ out) {
    const u32 P = offsets[NCELL];
    const int wv   = threadIdx.x >> 6;
    const int lane = threadIdx.x & 63;
    const u32 j0   = ((u32)blockIdx.x * 4u + (u32)wv) * 64u;
    if (j0 >= P) return;

    const uint2 pr  = sorted[j0 + (u32)lane];
    const float myw = __uint_as_float(pr.x);
    const int mycell = (int)(pr.y >> 14);
    int mypil = (int)(pr.y & 0x3FFFu);
    if (mypil >= NPILLAR) mypil = 0;          // dummy sentinel rows (w = 0)

    const int prev_cell = (j0 > 0) ? (int)(sorted[j0 - 1].y >> 14) : -1;
    const int next_cell = (int)(sorted[j0 + 64].y >> 14);

    const int upc = __shfl_up(mycell, 1);
    const unsigned long long bm = __ballot(lane == 0 || mycell != upc);

    float xr[8];
#pragma unroll
    for (int t = 0; t < 8; ++t)
        xr[t] = x_t[(size_t)rlane_i(mypil, t) * C_ + lane];

    float acc = 0.f;
    bool first = true;

#pragma unroll
    for (int t = 0; t < 64; ++t) {
        acc += rlane_f(myw, t) * xr[t & 7];
        if (t + 8 < 64)
            xr[t & 7] = x_t[(size_t)rlane_i(mypil, t + 8) * C_ + lane];
        const bool flush = (t == 63) || ((bm >> (t + 1)) & 1ull);
        if (flush) {
            const int cc = rlane_i(mycell, t);
            if (cc < NCELL) {
                float* dst = out + ((size_t)(cc >> 14) * C_ + lane) * BEVC
                           + (cc & (BEVC - 1));
                const bool spans = (first && cc == prev_cell)
                                || (t == 63 && next_cell == cc);
                if (spans) atomicAdd(dst, acc);
                else *dst = acc;
            }
            acc = 0.f;
            first = false;
        }
    }
}

// ---------------------------------------------------------------------------
extern "C" void kernel_launch(void* const* d_in, const int* in_sizes, int n_in,
                              void* d_out, int out_size, void* d_ws, size_t ws_size,
                              hipStream_t stream) {
    const float* feat  = (const float*)d_in[0];
    const float* intr  = (const float*)d_in[1];
    const float* extr  = (const float*)d_in[2];
    const float* w1    = (const float*)d_in[3];
    const float* b1    = (const float*)d_in[4];
    const float* gma   = (const float*)d_in[5];
    const float* bta   = (const float*)d_in[6];
    const float* mu    = (const float*)d_in[7];
    const float* var   = (const float*)d_in[8];
    const float* w2    = (const float*)d_in[9];
    const float* b2    = (const float*)d_in[10];
    float* out = (float*)d_out;

    // workspace layout (8B-aligned first)
    double* Mbuf    = (double*)d_ws;                                 // 864 B
    u32*    gcursor = (u32*)((char*)d_ws + 960);
    uint2*  sorted  = (uint2*)((char*)d_ws + 1024);                  // NPOINT+128
    uint2*  pc      = sorted + NPOINT + 128;                         // NPOINT
    float*  x_t     = (float*)(pc + NPOINT);                         // NPOINT
    float*  hpAll   = x_t + NPOINT;                                  // 4*NPOINT
    u32*    counts  = (u32*)(hpAll + 4 * (size_t)NPOINT);            // NCELL
    u32*    offs    = counts + NCELL;                                // NCELL+1
    float*  w2t     = (float*)(offs + NCELL + 1);                    // 4096

    k_init_conv<<<901, 256, 0, stream>>>(feat, w1, hpAll, x_t, w2, w2t,
                                         counts, gcursor, intr, extr, Mbuf);
    k_depth<<<NPILLAR / 4, 256, 0, stream>>>(hpAll, b1, gma, bta, mu, var,
                                             w2t, b2, Mbuf, extr, pc, counts);
    k_alloc<<<NCELL / 256, 256, 0, stream>>>(counts, offs, gcursor);
    k_zero_place<<<4161, 256, 0, stream>>>(pc, offs, counts, gcursor,
                                           sorted, &offs[NCELL], out);
    k_pool<<<NPOINT / 64 / 4, 256, 0, stream>>>(sorted, offs, x_t, out);

    (void)in_sizes; (void)n_in; (void)ws_size; (void)out_size;
}